// Round 13
// baseline (131.922 us; speedup 1.0000x reference)
//
// Flash-attention SDPA (GQA 16:4), MI355X gfx950.
// fp32 q in, fp32 out; K/V pre-converted to bf16 in d_ws (prologue kernel;
// R7 proved the main-vs-bench gap ~56 us is HARNESS-fixed, not prologue).
// XCD-local block mapping (g%8) keeps K/V L2-resident.
// S^T = K*Q^T keeps P in registers; max-free softmax; ones-MFMA row-sum;
// dbuf + 1 barrier/tile; t0 de-phase.
// PRODUCER-CONSUMER WAVE SPECIALIZATION (R9, 55.1 us).
// PAIRED-KT PV WITH 16x16x32 MFMA (R10, 49.7 us).
// setprio (R11) and kf-prefetch-ring (R12) both neutral/negative: compiler
// owns the schedule (VGPR stayed 64 with the ring = it collapsed it).
// This revision: 64 q PER COMPUTE WAVE. R10 accounting: LDS pipe is the
// top consumer at ~60% of the 7,455-cyc tile wall (compute reads 3,328 +
// stager writes 1,128 cyc/CU-tile); fragment reads are 32 KB/wave-tile
// REGARDLESS of q-rows (R5 invariant). 256-thr blocks, TM=128, grid 512:
// waves 0-1 compute 64 q each (4 mi-bands; kf/vf amortized 2x), waves
// 2-3 stagers (thread = full K row + V pair over 32 d). Compute LDS
// traffic halves: 256 -> 128 KB/CU-tile (pipe ~60% -> ~37%). Per-q-row
// math identical to R10 -> bit-identical absmax. Risks: 2 waves/SIMD
// (TLP), VGPR ~230 (launch_bounds(256,2)).
#include <hip/hip_runtime.h>
#include <hip/hip_bf16.h>

typedef unsigned short u16;
typedef short s16x4 __attribute__((ext_vector_type(4)));
typedef short s16x8 __attribute__((ext_vector_type(8)));
typedef float fx4 __attribute__((ext_vector_type(4)));
typedef unsigned ux2 __attribute__((ext_vector_type(2)));

#define BATCH 2
#define NHQ 16
#define NHKV 4
#define SEQ 2048
#define HD 64
#define TM 128
#define TN 128
#define NTILES (SEQ / TN)
#define VSTRIDE 132   // u16 row stride of shVt (66 dwords == 2 mod 32)
#define NKV (BATCH * NHKV * SEQ * HD)   // 1,048,576 elems per tensor
// (1/sqrt(HD)) * log2(e)
#define QSCALE 0.18033688011112042f

// {lo16: bf16(a), hi16: bf16(b)}, round-half-up (+0x8000) then byte-perm.
__device__ __forceinline__ unsigned pack2_bf16(float a, float b) {
    const unsigned ua = __float_as_uint(a) + 0x8000u;
    const unsigned ub = __float_as_uint(b) + 0x8000u;
    return __builtin_amdgcn_perm(ub, ua, 0x07060302u);
}
// interleave low/high u16 halves of two dwords (row0, row1 of V)
__device__ __forceinline__ unsigned ilv_lo(unsigned r0, unsigned r1) {
    return __builtin_amdgcn_perm(r1, r0, 0x05040100u);
}
__device__ __forceinline__ unsigned ilv_hi(unsigned r0, unsigned r1) {
    return __builtin_amdgcn_perm(r1, r0, 0x07060302u);
}

// Prologue: K,V fp32 -> bf16 into workspace. 1024 blocks x 256 thr x 4 elems.
__global__ __launch_bounds__(256) void cvt_kv_kernel(
    const float* __restrict__ K, const float* __restrict__ V,
    u16* __restrict__ wsK, u16* __restrict__ wsV)
{
    const int i = (blockIdx.x * 256 + threadIdx.x) * 4;
    const fx4 k4 = *(const fx4*)(K + i);
    const fx4 v4 = *(const fx4*)(V + i);
    ux2 ko, vo;
    ko[0] = pack2_bf16(k4[0], k4[1]);
    ko[1] = pack2_bf16(k4[2], k4[3]);
    vo[0] = pack2_bf16(v4[0], v4[1]);
    vo[1] = pack2_bf16(v4[2], v4[3]);
    *(ux2*)(wsK + i) = ko;
    *(ux2*)(wsV + i) = vo;
}

__global__ __launch_bounds__(256, 2) void ptSDPA_39668317946373_kernel(
    const float* __restrict__ gQ,
    const u16* __restrict__ wsK,
    const u16* __restrict__ wsV,
    float* __restrict__ gO)
{
    // Double-buffered tiles: 2 x (16 + 16.5) KB = 65 KB -> 2 blocks/CU.
    __shared__ u16 shK[2][TN * HD];        // [buf][key][d], XOR-chunk swizzle
    __shared__ u16 shVt[2][HD * VSTRIDE];  // [buf][d][key], padded stride

    const int tid = threadIdx.x;
    const int wv  = tid >> 6;       // 0..3
    const int ln  = tid & 63;
    const int l15 = ln & 15;
    const int qd  = ln >> 4;        // quad 0..3

    // XCD-local decode: g%8 = kv-group (= batch*NHKV + hkv).
    const int g     = blockIdx.x;
    const int kvg   = g & 7;
    const int inner = g >> 3;        // 0..63
    const int qtb   = inner & 15;
    const int hqw   = inner >> 4;    // 0..3
    const int batch = kvg >> 2;
    const int hkv   = kvg & 3;
    const int head  = batch * NHQ + hkv * 4 + hqw;

    // De-phase: co-resident blocks start their tile loop at different
    // rotations so their compute phases decorrelate.
    const int t0 = (inner & 3) * 4;

    const float* q_base = gQ + (size_t)head * SEQ * HD;
    const u16*   k_base = wsK + (size_t)kvg * SEQ * HD;
    const u16*   v_base = wsV + (size_t)kvg * SEQ * HD;
    float*       o_base = gO + (size_t)head * SEQ * HD;

    const int qrow0 = qtb * TM;

    // Role split (wave-uniform): waves 0-1 compute (64 q-rows each, four
    // 16-row bands mi=0..3); waves 2-3 stage K AND V for the whole block.
    const bool isC = (wv < 2);

    // ---- Compute-wave state ----
    s16x8 qfrag[4][2];
    fx4 oacc[4][4];
    fx4 racc[4];
    const fx4 z4 = {0.f, 0.f, 0.f, 0.f};
#pragma unroll
    for (int mi = 0; mi < 4; mi++) {
        racc[mi] = z4;
#pragma unroll
        for (int ni = 0; ni < 4; ni++) oacc[mi][ni] = z4;
    }
    // B-operand of the row-sum MFMA: all-ones bf16 (K=32 wide).
    const s16x8 ones8 = {(short)0x3F80, (short)0x3F80, (short)0x3F80,
                         (short)0x3F80, (short)0x3F80, (short)0x3F80,
                         (short)0x3F80, (short)0x3F80};

    if (isC) {
        // Q fragments (B-operand of S^T MFMA: lane&15 = q, k = quad*8+j),
        // pre-scaled by QSCALE. Bands at rows qrow0 + wv*64 + mi*16.
#pragma unroll
        for (int mi = 0; mi < 4; mi++) {
            const int row = qrow0 + wv * 64 + mi * 16 + l15;
#pragma unroll
            for (int ks = 0; ks < 2; ks++) {
                const int d0 = ks * 32 + qd * 8;
                const fx4 lo = *(const fx4*)(q_base + (size_t)row * HD + d0);
                const fx4 hi = *(const fx4*)(q_base + (size_t)row * HD + d0 + 4);
                union { unsigned u[4]; s16x8 v; } t;
                t.u[0] = pack2_bf16(lo[0] * QSCALE, lo[1] * QSCALE);
                t.u[1] = pack2_bf16(lo[2] * QSCALE, lo[3] * QSCALE);
                t.u[2] = pack2_bf16(hi[0] * QSCALE, hi[1] * QSCALE);
                t.u[3] = pack2_bf16(hi[2] * QSCALE, hi[3] * QSCALE);
                qfrag[mi][ks] = t.v;
            }
        }
    }

    // ---- Stager-wave state (st = 0..127 over waves 2-3) ----
    const int st = tid - 128;
    // K role: one FULL key row (64 d, 8 chunks).
    const int skey = st & 127;
    const u16* kp0 = k_base + skey * HD;
    // V role: a key PAIR (2*(st&63)) over 32 d (two 16-d halves).
    const int vkey = (st & 63) * 2;
    const int vd0  = (st >> 6) * 32;
    const u16* vp0 = v_base + vkey * HD + vd0;

    if (!isC) {
        // First tile (t0): load then stage into buffer 0.
        s16x8 kreg[8], vreg[8];
        const u16* kp = kp0 + (size_t)t0 * TN * HD;
        const u16* vp = vp0 + (size_t)t0 * TN * HD;
#pragma unroll
        for (int s = 0; s < 8; s++) kreg[s] = *(const s16x8*)(kp + s * 8);
#pragma unroll
        for (int s = 0; s < 4; s++) {
            vreg[s]     = *(const s16x8*)(vp + s * 8);
            vreg[4 + s] = *(const s16x8*)(vp + HD + s * 8);
        }
#pragma unroll
        for (int c = 0; c < 8; c++)
            *(s16x8*)(shK[0] + skey * 64 + ((c ^ (skey & 7)) * 8)) = kreg[c];
#pragma unroll
        for (int h = 0; h < 4; h++) {
            union { s16x8 v; unsigned u[4]; } r0, r1;
            r0.v = vreg[h];
            r1.v = vreg[4 + h];
#pragma unroll
            for (int c2 = 0; c2 < 4; c2++) {
                const int d = vd0 + h * 8 + c2 * 2;
                *(unsigned*)(shVt[0] + d * VSTRIDE + vkey) =
                    ilv_lo(r0.u[c2], r1.u[c2]);
                *(unsigned*)(shVt[0] + (d + 1) * VSTRIDE + vkey) =
                    ilv_hi(r0.u[c2], r1.u[c2]);
            }
        }
    }

#pragma unroll 2
    for (int i = 0; i < NTILES; i++) {
        const int cur = i & 1;
        const int nxt = cur ^ 1;

        // Single barrier per tile: buf[cur] staged AND buf[nxt] readers done.
        __syncthreads();

        if (isC) {
            // Paired-kt pipeline over 4 pairs (32 keys each), skew-1:
            // QK(pair+1) in flight while exp2/pack(pair) runs on the VALU,
            // then PV(pair) as full-width 16x16x32 MFMAs. 4 mi bands share
            // every kf/vf fragment read (the whole point of this revision).
            const int kb7 = l15 & 7;
            const int sw0 = (qd ^ kb7) << 3;          // ks=0 chunk swizzle
            const int sw1 = ((4 + qd) ^ kb7) << 3;    // ks=1 chunk swizzle
            const u16* kRow = shK[cur] + l15 * 64;

            fx4 scp[2][2][4];   // [pair&1][kt-in-pair][mi]
            // QK(pair 0): kt = 0,1
#pragma unroll
            for (int kt2 = 0; kt2 < 2; kt2++) {
                const s16x8 kf0 = *(const s16x8*)(kRow + kt2 * 1024 + sw0);
                const s16x8 kf1 = *(const s16x8*)(kRow + kt2 * 1024 + sw1);
#pragma unroll
                for (int mi = 0; mi < 4; mi++) {
                    fx4 s = __builtin_amdgcn_mfma_f32_16x16x32_bf16(
                        kf0, qfrag[mi][0], z4, 0, 0, 0);
                    s = __builtin_amdgcn_mfma_f32_16x16x32_bf16(
                        kf1, qfrag[mi][1], s, 0, 0, 0);
                    scp[0][kt2][mi] = s;
                }
            }

#pragma unroll
            for (int jp = 0; jp < 4; jp++) {
                const int pp = jp & 1;

                // V B-fragments for this pair (shared by all 4 mi bands).
                const int kbase = jp * 32 + qd * 4;
                s16x8 vf8[4];
#pragma unroll
                for (int ni = 0; ni < 4; ni++) {
                    const u16* row = shVt[cur] + (ni * 16 + l15) * VSTRIDE;
                    union { s16x4 h[2]; s16x8 v; } u;
                    u.h[0] = *(const s16x4*)(row + kbase);
                    u.h[1] = *(const s16x4*)(row + kbase + 16);
                    vf8[ni] = u.v;
                }

                if (jp < 3) {   // QK(pair jp+1): kt = 2jp+2, 2jp+3
#pragma unroll
                    for (int kt2 = 0; kt2 < 2; kt2++) {
                        const int kt = (jp + 1) * 2 + kt2;
                        const s16x8 kf0 =
                            *(const s16x8*)(kRow + kt * 1024 + sw0);
                        const s16x8 kf1 =
                            *(const s16x8*)(kRow + kt * 1024 + sw1);
#pragma unroll
                        for (int mi = 0; mi < 4; mi++) {
                            fx4 s = __builtin_amdgcn_mfma_f32_16x16x32_bf16(
                                kf0, qfrag[mi][0], z4, 0, 0, 0);
                            s = __builtin_amdgcn_mfma_f32_16x16x32_bf16(
                                kf1, qfrag[mi][1], s, 0, 0, 0);
                            scp[pp ^ 1][kt2][mi] = s;
                        }
                    }
                }

                // exp2 + pack into the 16x16x32 A-fragment:
                // k = qd*8 + j; j=0..3 <- P[kt even, r=j], j=4..7 <- P[kt
                // odd, r=j-4]. (lane&15 = q, consistent with S^T C layout.)
#pragma unroll
                for (int mi = 0; mi < 4; mi++) {
                    const float e0 = __builtin_amdgcn_exp2f(scp[pp][0][mi][0]);
                    const float e1 = __builtin_amdgcn_exp2f(scp[pp][0][mi][1]);
                    const float e2 = __builtin_amdgcn_exp2f(scp[pp][0][mi][2]);
                    const float e3 = __builtin_amdgcn_exp2f(scp[pp][0][mi][3]);
                    const float f0 = __builtin_amdgcn_exp2f(scp[pp][1][mi][0]);
                    const float f1 = __builtin_amdgcn_exp2f(scp[pp][1][mi][1]);
                    const float f2 = __builtin_amdgcn_exp2f(scp[pp][1][mi][2]);
                    const float f3 = __builtin_amdgcn_exp2f(scp[pp][1][mi][3]);
                    union { unsigned u[4]; s16x8 v; } pk;
                    pk.u[0] = pack2_bf16(e0, e1);
                    pk.u[1] = pack2_bf16(e2, e3);
                    pk.u[2] = pack2_bf16(f0, f1);
                    pk.u[3] = pack2_bf16(f2, f3);
                    const s16x8 af = pk.v;

                    // Row sum + PV on the matrix pipe (K=32 per MFMA).
                    racc[mi] = __builtin_amdgcn_mfma_f32_16x16x32_bf16(
                        af, ones8, racc[mi], 0, 0, 0);
#pragma unroll
                    for (int ni = 0; ni < 4; ni++)
                        oacc[mi][ni] = __builtin_amdgcn_mfma_f32_16x16x32_bf16(
                            af, vf8[ni], oacc[mi][ni], 0, 0, 0);
                }
            }
        } else {
            // Stager waves: load tile t0+i+1 from L2 and stage into
            // buf[nxt] (no extra barrier: buf[nxt] is not read until after
            // the next loop-top barrier).
            if (i + 1 < NTILES) {
                const int tp = (t0 + i + 1) & (NTILES - 1);
                s16x8 kreg[8], vreg[8];
                const u16* kp = kp0 + (size_t)tp * TN * HD;
                const u16* vp = vp0 + (size_t)tp * TN * HD;
#pragma unroll
                for (int s = 0; s < 8; s++)
                    kreg[s] = *(const s16x8*)(kp + s * 8);
#pragma unroll
                for (int s = 0; s < 4; s++) {
                    vreg[s]     = *(const s16x8*)(vp + s * 8);
                    vreg[4 + s] = *(const s16x8*)(vp + HD + s * 8);
                }
#pragma unroll
                for (int c = 0; c < 8; c++)
                    *(s16x8*)(shK[nxt] + skey * 64 + ((c ^ (skey & 7)) * 8)) =
                        kreg[c];
#pragma unroll
                for (int h = 0; h < 4; h++) {
                    union { s16x8 v; unsigned u[4]; } r0, r1;
                    r0.v = vreg[h];
                    r1.v = vreg[4 + h];
#pragma unroll
                    for (int c2 = 0; c2 < 4; c2++) {
                        const int d = vd0 + h * 8 + c2 * 2;
                        *(unsigned*)(shVt[nxt] + d * VSTRIDE + vkey) =
                            ilv_lo(r0.u[c2], r1.u[c2]);
                        *(unsigned*)(shVt[nxt] + (d + 1) * VSTRIDE + vkey) =
                            ilv_hi(r0.u[c2], r1.u[c2]);
                    }
                }
            }
        }
    }

    // Epilogue (compute waves only): racc holds full row sums (q = qd*4+r);
    // normalize, store fp32. No cross-lane reduction needed.
    if (isC) {
#pragma unroll
        for (int mi = 0; mi < 4; mi++) {
            float inv[4];
#pragma unroll
            for (int r = 0; r < 4; r++) inv[r] = 1.0f / racc[mi][r];
#pragma unroll
            for (int ni = 0; ni < 4; ni++)
#pragma unroll
                for (int r = 0; r < 4; r++) {
                    const int qr = qrow0 + wv * 64 + mi * 16 + qd * 4 + r;
                    o_base[(size_t)qr * HD + ni * 16 + l15] =
                        oacc[mi][ni][r] * inv[r];
                }
        }
    }
}

extern "C" void kernel_launch(void* const* d_in, const int* in_sizes, int n_in,
                              void* d_out, int out_size, void* d_ws, size_t ws_size,
                              hipStream_t stream) {
    const float* q = (const float*)d_in[0];
    const float* k = (const float*)d_in[1];
    const float* v = (const float*)d_in[2];
    float*       o = (float*)d_out;
    u16* wsK = (u16*)d_ws;            // 2 MB
    u16* wsV = wsK + NKV;             // 2 MB  (4 MB total workspace)
    cvt_kv_kernel<<<NKV / 1024, 256, 0, stream>>>(k, v, wsK, wsV);
    const dim3 grid(BATCH * NHQ * (SEQ / TM));   // 512 workgroups, 256 thr
    ptSDPA_39668317946373_kernel<<<grid, 256, 0, stream>>>(q, wsK, wsV, o);
}

// Round 14
// 110.944 us; speedup vs baseline: 1.1891x; 1.1891x over previous
//
// Flash-attention SDPA (GQA 16:4), MI355X gfx950.
// fp32 q in, fp32 out; K/V pre-converted to bf16 in d_ws (prologue kernel;
// R7 proved the main-vs-bench gap ~56 us is HARNESS-fixed, not prologue).
// XCD-local block mapping (g%8) keeps K/V L2-resident.
// S^T = K*Q^T keeps P in registers; max-free softmax; ones-MFMA row-sum;
// dbuf + 1 barrier/tile.
// PRODUCER-CONSUMER WAVE SPECIALIZATION (R9, 55.1 us).
// PAIRED-KT PV WITH 16x16x32 MFMA (R10, 49.7 us).
// setprio (R11), kf-ring (R12): neutral/negative, reverted.
// R13 (64q waves, 4-wave blocks): 75.7 us REGRESSION -- but counters show
// why: waves round-robin onto SIMDs, so waves 0-1 = compute put ALL
// compute on SIMDs 0-1 of each CU (MfmaUtil 19.8% ~ half of R10's
// pattern; 2 SIMDs idle). The LDS-traffic halving itself worked.
// This revision: TM=256, 512-thr 8-wave blocks -- same 64q/wave LDS
// amortization with CORRECT placement: waves 0-3 compute (one per SIMD,
// mi=4 bands), waves 4-7 stagers (R10 stager code verbatim). Grid 256 =
// 1 block/CU; per-SIMD matrix demand identical to R10 (144 MFMA/tile);
// compute LDS reads/CU-tile halve (256->128 KB) AND staging writes halve
// (one block stages per CU). launch_bounds(512,2) -> 256 VGPR cap.
#include <hip/hip_runtime.h>
#include <hip/hip_bf16.h>

typedef unsigned short u16;
typedef short s16x4 __attribute__((ext_vector_type(4)));
typedef short s16x8 __attribute__((ext_vector_type(8)));
typedef float fx4 __attribute__((ext_vector_type(4)));
typedef unsigned ux2 __attribute__((ext_vector_type(2)));

#define BATCH 2
#define NHQ 16
#define NHKV 4
#define SEQ 2048
#define HD 64
#define TM 256
#define TN 128
#define NTILES (SEQ / TN)
#define VSTRIDE 132   // u16 row stride of shVt (66 dwords == 2 mod 32)
#define NKV (BATCH * NHKV * SEQ * HD)   // 1,048,576 elems per tensor
// (1/sqrt(HD)) * log2(e)
#define QSCALE 0.18033688011112042f

// {lo16: bf16(a), hi16: bf16(b)}, round-half-up (+0x8000) then byte-perm.
__device__ __forceinline__ unsigned pack2_bf16(float a, float b) {
    const unsigned ua = __float_as_uint(a) + 0x8000u;
    const unsigned ub = __float_as_uint(b) + 0x8000u;
    return __builtin_amdgcn_perm(ub, ua, 0x07060302u);
}
// interleave low/high u16 halves of two dwords (row0, row1 of V)
__device__ __forceinline__ unsigned ilv_lo(unsigned r0, unsigned r1) {
    return __builtin_amdgcn_perm(r1, r0, 0x05040100u);
}
__device__ __forceinline__ unsigned ilv_hi(unsigned r0, unsigned r1) {
    return __builtin_amdgcn_perm(r1, r0, 0x07060302u);
}

// Prologue: K,V fp32 -> bf16 into workspace. 1024 blocks x 256 thr x 4 elems.
__global__ __launch_bounds__(256) void cvt_kv_kernel(
    const float* __restrict__ K, const float* __restrict__ V,
    u16* __restrict__ wsK, u16* __restrict__ wsV)
{
    const int i = (blockIdx.x * 256 + threadIdx.x) * 4;
    const fx4 k4 = *(const fx4*)(K + i);
    const fx4 v4 = *(const fx4*)(V + i);
    ux2 ko, vo;
    ko[0] = pack2_bf16(k4[0], k4[1]);
    ko[1] = pack2_bf16(k4[2], k4[3]);
    vo[0] = pack2_bf16(v4[0], v4[1]);
    vo[1] = pack2_bf16(v4[2], v4[3]);
    *(ux2*)(wsK + i) = ko;
    *(ux2*)(wsV + i) = vo;
}

__global__ __launch_bounds__(512, 2) void ptSDPA_39668317946373_kernel(
    const float* __restrict__ gQ,
    const u16* __restrict__ wsK,
    const u16* __restrict__ wsV,
    float* __restrict__ gO)
{
    // Double-buffered tiles: 2 x (16 + 16.5) KB = 65 KB; 1 block/CU (grid).
    __shared__ u16 shK[2][TN * HD];        // [buf][key][d], XOR-chunk swizzle
    __shared__ u16 shVt[2][HD * VSTRIDE];  // [buf][d][key], padded stride

    const int tid = threadIdx.x;
    const int wv  = tid >> 6;       // 0..7
    const int ln  = tid & 63;
    const int l15 = ln & 15;
    const int qd  = ln >> 4;        // quad 0..3

    // XCD-local decode: g%8 = kv-group (= batch*NHKV + hkv). Grid 256.
    const int g     = blockIdx.x;
    const int kvg   = g & 7;
    const int inner = g >> 3;        // 0..31
    const int qtb   = inner & 7;     // 8 q-tiles of 256 rows
    const int hqw   = inner >> 3;    // 0..3
    const int batch = kvg >> 2;
    const int hkv   = kvg & 3;
    const int head  = batch * NHQ + hkv * 4 + hqw;

    // Tile-order rotation (L2 spread across blocks of the same kvg).
    const int t0 = (inner & 3) * 4;

    const float* q_base = gQ + (size_t)head * SEQ * HD;
    const u16*   k_base = wsK + (size_t)kvg * SEQ * HD;
    const u16*   v_base = wsV + (size_t)kvg * SEQ * HD;
    float*       o_base = gO + (size_t)head * SEQ * HD;

    const int qrow0 = qtb * TM;

    // Role split (wave-uniform): waves 0-3 compute (64 q-rows each, four
    // 16-row bands mi=0..3) -> one compute wave per SIMD; waves 4-7 stage.
    const bool isC = (wv < 4);

    // ---- Compute-wave state ----
    s16x8 qfrag[4][2];
    fx4 oacc[4][4];
    fx4 racc[4];
    const fx4 z4 = {0.f, 0.f, 0.f, 0.f};
#pragma unroll
    for (int mi = 0; mi < 4; mi++) {
        racc[mi] = z4;
#pragma unroll
        for (int ni = 0; ni < 4; ni++) oacc[mi][ni] = z4;
    }
    // B-operand of the row-sum MFMA: all-ones bf16 (K=32 wide).
    const s16x8 ones8 = {(short)0x3F80, (short)0x3F80, (short)0x3F80,
                         (short)0x3F80, (short)0x3F80, (short)0x3F80,
                         (short)0x3F80, (short)0x3F80};

    if (isC) {
        // Q fragments (B-operand of S^T MFMA: lane&15 = q, k = quad*8+j),
        // pre-scaled by QSCALE. Bands at rows qrow0 + wv*64 + mi*16.
#pragma unroll
        for (int mi = 0; mi < 4; mi++) {
            const int row = qrow0 + wv * 64 + mi * 16 + l15;
#pragma unroll
            for (int ks = 0; ks < 2; ks++) {
                const int d0 = ks * 32 + qd * 8;
                const fx4 lo = *(const fx4*)(q_base + (size_t)row * HD + d0);
                const fx4 hi = *(const fx4*)(q_base + (size_t)row * HD + d0 + 4);
                union { unsigned u[4]; s16x8 v; } t;
                t.u[0] = pack2_bf16(lo[0] * QSCALE, lo[1] * QSCALE);
                t.u[1] = pack2_bf16(lo[2] * QSCALE, lo[3] * QSCALE);
                t.u[2] = pack2_bf16(hi[0] * QSCALE, hi[1] * QSCALE);
                t.u[3] = pack2_bf16(hi[2] * QSCALE, hi[3] * QSCALE);
                qfrag[mi][ks] = t.v;
            }
        }
    }

    // ---- Stager-wave state (st = 0..255 over waves 4-7; R10 pattern) ----
    const int st = tid - 256;
    // K role: one key row, half the head dim (32 d, bf16).
    const int skey  = st & 127;
    const int shalf = st >> 7;
    const u16* kp0 = k_base + skey * HD + shalf * 32;
    // V role: a key PAIR (2*(st&63)) over 16 d (group's band).
    const int vkey = (st & 63) * 2;
    const int vd0  = (st >> 6) * 16;
    const u16* vp0 = v_base + vkey * HD + vd0;

    if (!isC) {
        // First tile (t0): load then stage into buffer 0.
        s16x8 kreg[4], vreg[4];
        const u16* kp = kp0 + (size_t)t0 * TN * HD;
        const u16* vp = vp0 + (size_t)t0 * TN * HD;
#pragma unroll
        for (int s = 0; s < 4; s++) kreg[s] = *(const s16x8*)(kp + s * 8);
        vreg[0] = *(const s16x8*)(vp);
        vreg[1] = *(const s16x8*)(vp + 8);
        vreg[2] = *(const s16x8*)(vp + HD);
        vreg[3] = *(const s16x8*)(vp + HD + 8);
#pragma unroll
        for (int s = 0; s < 4; s++) {
            const int c = shalf * 4 + s;
            *(s16x8*)(shK[0] + skey * 64 + ((c ^ (skey & 7)) * 8)) = kreg[s];
        }
#pragma unroll
        for (int h = 0; h < 2; h++) {
            union { s16x8 v; unsigned u[4]; } r0, r1;
            r0.v = vreg[h];
            r1.v = vreg[2 + h];
#pragma unroll
            for (int c2 = 0; c2 < 4; c2++) {
                const int d = vd0 + h * 8 + c2 * 2;
                *(unsigned*)(shVt[0] + d * VSTRIDE + vkey) =
                    ilv_lo(r0.u[c2], r1.u[c2]);
                *(unsigned*)(shVt[0] + (d + 1) * VSTRIDE + vkey) =
                    ilv_hi(r0.u[c2], r1.u[c2]);
            }
        }
    }

#pragma unroll 2
    for (int i = 0; i < NTILES; i++) {
        const int cur = i & 1;
        const int nxt = cur ^ 1;

        // Single barrier per tile: buf[cur] staged AND buf[nxt] readers done.
        __syncthreads();

        if (isC) {
            // Paired-kt pipeline over 4 pairs (32 keys each), skew-1:
            // QK(pair+1) in flight while exp2/pack(pair) runs on the VALU,
            // then PV(pair) as full-width 16x16x32 MFMAs. 4 mi bands share
            // every kf/vf fragment read (the LDS amortization).
            const int kb7 = l15 & 7;
            const int sw0 = (qd ^ kb7) << 3;          // ks=0 chunk swizzle
            const int sw1 = ((4 + qd) ^ kb7) << 3;    // ks=1 chunk swizzle
            const u16* kRow = shK[cur] + l15 * 64;

            fx4 scp[2][2][4];   // [pair&1][kt-in-pair][mi]
            // QK(pair 0): kt = 0,1
#pragma unroll
            for (int kt2 = 0; kt2 < 2; kt2++) {
                const s16x8 kf0 = *(const s16x8*)(kRow + kt2 * 1024 + sw0);
                const s16x8 kf1 = *(const s16x8*)(kRow + kt2 * 1024 + sw1);
#pragma unroll
                for (int mi = 0; mi < 4; mi++) {
                    fx4 s = __builtin_amdgcn_mfma_f32_16x16x32_bf16(
                        kf0, qfrag[mi][0], z4, 0, 0, 0);
                    s = __builtin_amdgcn_mfma_f32_16x16x32_bf16(
                        kf1, qfrag[mi][1], s, 0, 0, 0);
                    scp[0][kt2][mi] = s;
                }
            }

#pragma unroll
            for (int jp = 0; jp < 4; jp++) {
                const int pp = jp & 1;

                // V B-fragments for this pair (shared by all 4 mi bands).
                const int kbase = jp * 32 + qd * 4;
                s16x8 vf8[4];
#pragma unroll
                for (int ni = 0; ni < 4; ni++) {
                    const u16* row = shVt[cur] + (ni * 16 + l15) * VSTRIDE;
                    union { s16x4 h[2]; s16x8 v; } u;
                    u.h[0] = *(const s16x4*)(row + kbase);
                    u.h[1] = *(const s16x4*)(row + kbase + 16);
                    vf8[ni] = u.v;
                }

                if (jp < 3) {   // QK(pair jp+1): kt = 2jp+2, 2jp+3
#pragma unroll
                    for (int kt2 = 0; kt2 < 2; kt2++) {
                        const int kt = (jp + 1) * 2 + kt2;
                        const s16x8 kf0 =
                            *(const s16x8*)(kRow + kt * 1024 + sw0);
                        const s16x8 kf1 =
                            *(const s16x8*)(kRow + kt * 1024 + sw1);
#pragma unroll
                        for (int mi = 0; mi < 4; mi++) {
                            fx4 s = __builtin_amdgcn_mfma_f32_16x16x32_bf16(
                                kf0, qfrag[mi][0], z4, 0, 0, 0);
                            s = __builtin_amdgcn_mfma_f32_16x16x32_bf16(
                                kf1, qfrag[mi][1], s, 0, 0, 0);
                            scp[pp ^ 1][kt2][mi] = s;
                        }
                    }
                }

                // exp2 + pack into the 16x16x32 A-fragment:
                // k = qd*8 + j; j=0..3 <- P[kt even, r=j], j=4..7 <- P[kt
                // odd, r=j-4]. (lane&15 = q, consistent with S^T C layout.)
#pragma unroll
                for (int mi = 0; mi < 4; mi++) {
                    const float e0 = __builtin_amdgcn_exp2f(scp[pp][0][mi][0]);
                    const float e1 = __builtin_amdgcn_exp2f(scp[pp][0][mi][1]);
                    const float e2 = __builtin_amdgcn_exp2f(scp[pp][0][mi][2]);
                    const float e3 = __builtin_amdgcn_exp2f(scp[pp][0][mi][3]);
                    const float f0 = __builtin_amdgcn_exp2f(scp[pp][1][mi][0]);
                    const float f1 = __builtin_amdgcn_exp2f(scp[pp][1][mi][1]);
                    const float f2 = __builtin_amdgcn_exp2f(scp[pp][1][mi][2]);
                    const float f3 = __builtin_amdgcn_exp2f(scp[pp][1][mi][3]);
                    union { unsigned u[4]; s16x8 v; } pk;
                    pk.u[0] = pack2_bf16(e0, e1);
                    pk.u[1] = pack2_bf16(e2, e3);
                    pk.u[2] = pack2_bf16(f0, f1);
                    pk.u[3] = pack2_bf16(f2, f3);
                    const s16x8 af = pk.v;

                    // Row sum + PV on the matrix pipe (K=32 per MFMA).
                    racc[mi] = __builtin_amdgcn_mfma_f32_16x16x32_bf16(
                        af, ones8, racc[mi], 0, 0, 0);
#pragma unroll
                    for (int ni = 0; ni < 4; ni++)
                        oacc[mi][ni] = __builtin_amdgcn_mfma_f32_16x16x32_bf16(
                            af, vf8[ni], oacc[mi][ni], 0, 0, 0);
                }
            }
        } else {
            // Stager waves: load tile t0+i+1 from L2 and stage into
            // buf[nxt] (no extra barrier: buf[nxt] is not read until after
            // the next loop-top barrier).
            if (i + 1 < NTILES) {
                const int tp = (t0 + i + 1) & (NTILES - 1);
                s16x8 kreg[4], vreg[4];
                const u16* kp = kp0 + (size_t)tp * TN * HD;
                const u16* vp = vp0 + (size_t)tp * TN * HD;
#pragma unroll
                for (int s = 0; s < 4; s++)
                    kreg[s] = *(const s16x8*)(kp + s * 8);
                vreg[0] = *(const s16x8*)(vp);
                vreg[1] = *(const s16x8*)(vp + 8);
                vreg[2] = *(const s16x8*)(vp + HD);
                vreg[3] = *(const s16x8*)(vp + HD + 8);
#pragma unroll
                for (int s = 0; s < 4; s++) {
                    const int c = shalf * 4 + s;
                    *(s16x8*)(shK[nxt] + skey * 64 + ((c ^ (skey & 7)) * 8)) =
                        kreg[s];
                }
#pragma unroll
                for (int h = 0; h < 2; h++) {
                    union { s16x8 v; unsigned u[4]; } r0, r1;
                    r0.v = vreg[h];
                    r1.v = vreg[2 + h];
#pragma unroll
                    for (int c2 = 0; c2 < 4; c2++) {
                        const int d = vd0 + h * 8 + c2 * 2;
                        *(unsigned*)(shVt[nxt] + d * VSTRIDE + vkey) =
                            ilv_lo(r0.u[c2], r1.u[c2]);
                        *(unsigned*)(shVt[nxt] + (d + 1) * VSTRIDE + vkey) =
                            ilv_hi(r0.u[c2], r1.u[c2]);
                    }
                }
            }
        }
    }

    // Epilogue (compute waves only): racc holds full row sums (q = qd*4+r);
    // normalize, store fp32. No cross-lane reduction needed.
    if (isC) {
#pragma unroll
        for (int mi = 0; mi < 4; mi++) {
            float inv[4];
#pragma unroll
            for (int r = 0; r < 4; r++) inv[r] = 1.0f / racc[mi][r];
#pragma unroll
            for (int ni = 0; ni < 4; ni++)
#pragma unroll
                for (int r = 0; r < 4; r++) {
                    const int qr = qrow0 + wv * 64 + mi * 16 + qd * 4 + r;
                    o_base[(size_t)qr * HD + ni * 16 + l15] =
                        oacc[mi][ni][r] * inv[r];
                }
        }
    }
}

extern "C" void kernel_launch(void* const* d_in, const int* in_sizes, int n_in,
                              void* d_out, int out_size, void* d_ws, size_t ws_size,
                              hipStream_t stream) {
    const float* q = (const float*)d_in[0];
    const float* k = (const float*)d_in[1];
    const float* v = (const float*)d_in[2];
    float*       o = (float*)d_out;
    u16* wsK = (u16*)d_ws;            // 2 MB
    u16* wsV = wsK + NKV;             // 2 MB  (4 MB total workspace)
    cvt_kv_kernel<<<NKV / 1024, 256, 0, stream>>>(k, v, wsK, wsV);
    const dim3 grid(BATCH * NHQ * (SEQ / TM));   // 256 workgroups, 512 thr
    ptSDPA_39668317946373_kernel<<<grid, 512, 0, stream>>>(q, wsK, wsV, o);
}